// Round 7
// baseline (1039.978 us; speedup 1.0000x reference)
//
#include <hip/hip_runtime.h>

#define DD   32
#define BKT  128      // dsts per bucket (power of two)
#define BSH  7        // log2(BKT)
#define PCH  4096     // edges per partition/hist block
#define MAXB 2048     // padded bucket-count (>= nbkt)
#define NB   256      // scan blocks per array
#define NT   256      // scan threads per block
#define SORTCAP 8192  // max edges per bucket for in-place sort (mean ~1280)

// ---------- bucket histogram (both relations, LDS pre-aggregated) ------------
__global__ void k_bhist(const int* __restrict__ dstA, int* __restrict__ cntA,
                        const int* __restrict__ dstB, int* __restrict__ cntB,
                        int E, int blocksPer) {
    __shared__ int h[MAXB];
    int b = blockIdx.x;
    const int* dst = (b < blocksPer) ? dstA : dstB;
    int* cnt       = (b < blocksPer) ? cntA : cntB;
    int bb         = (b < blocksPer) ? b : b - blocksPer;
    int t = threadIdx.x;
    for (int i = t; i < MAXB; i += 256) h[i] = 0;
    __syncthreads();
    int lo = bb * PCH;
    for (int k = 0; k < PCH / 256; ++k) {
        int i = lo + t + k * 256;
        if (i < E) atomicAdd(&h[dst[i] >> BSH], 1);
    }
    __syncthreads();
    for (int i = t; i < MAXB; i += 256) { int c = h[i]; if (c) atomicAdd(&cnt[i], c); }
}

// ---------- scan bucket counts -> gscan[nbkt+1] and cursor copy --------------
__global__ void k_bscan(const int* __restrict__ cntA, int* __restrict__ gsA, int* __restrict__ curA, int nbktA,
                        const int* __restrict__ cntB, int* __restrict__ gsB, int* __restrict__ curB, int nbktB) {
    __shared__ int sh[MAXB];
    __shared__ int red[256];
    int t = threadIdx.x;
    for (int sel = 0; sel < 2; ++sel) {
        const int* cnt = sel ? cntB : cntA;
        int* gs  = sel ? gsB : gsA;
        int* cur = sel ? curB : curA;
        int nbkt = sel ? nbktB : nbktA;
        for (int i = t; i < MAXB; i += 256) sh[i] = (i < nbkt) ? cnt[i] : 0;
        __syncthreads();
        int base = t * 8;
        int loc[8]; int tot = 0;
        for (int j = 0; j < 8; ++j) { loc[j] = sh[base + j]; tot += loc[j]; }
        red[t] = tot;
        __syncthreads();
        for (int off = 1; off < 256; off <<= 1) {
            int v = (t >= off) ? red[t - off] : 0;
            __syncthreads();
            red[t] += v;
            __syncthreads();
        }
        int run = red[t] - tot;
        for (int j = 0; j < 8; ++j) { sh[base + j] = run; run += loc[j]; }
        __syncthreads();
        for (int i = t; i < nbkt; i += 256) { gs[i] = sh[i]; cur[i] = sh[i]; }
        if (t == 255) gs[nbkt] = red[255];
        __syncthreads();
    }
}

// ---------- partition: staged[pos] = (src<<BSH) | (dst & (BKT-1)) ------------
__global__ void k_part(const int* __restrict__ srcA, const int* __restrict__ dstA,
                       int* __restrict__ curA, int* __restrict__ stA,
                       const int* __restrict__ srcB, const int* __restrict__ dstB,
                       int* __restrict__ curB, int* __restrict__ stB,
                       int E, int blocksPer) {
    __shared__ int pk[PCH];
    __shared__ unsigned short bkl[PCH];
    __shared__ int hist[MAXB];
    __shared__ int basev[MAXB];
    __shared__ int gb[MAXB];
    __shared__ int red[256];
    int b = blockIdx.x;
    const int* src; const int* dst; int* cur; int* st; int bb;
    if (b < blocksPer) { src = srcA; dst = dstA; cur = curA; st = stA; bb = b; }
    else               { src = srcB; dst = dstB; cur = curB; st = stB; bb = b - blocksPer; }
    int t = threadIdx.x;
    int lo = bb * PCH;
    int cntE = E - lo; if (cntE > PCH) cntE = PCH;

    for (int i = t; i < MAXB; i += 256) hist[i] = 0;
    __syncthreads();
    for (int k = 0; k < PCH / 256; ++k) {
        int i = t + k * 256;
        if (i < cntE) atomicAdd(&hist[dst[lo + i] >> BSH], 1);
    }
    __syncthreads();
    {
        int base = t * 8;
        int loc[8]; int tot = 0;
        for (int j = 0; j < 8; ++j) { loc[j] = hist[base + j]; tot += loc[j]; }
        red[t] = tot;
        __syncthreads();
        for (int off = 1; off < 256; off <<= 1) {
            int v = (t >= off) ? red[t - off] : 0;
            __syncthreads();
            red[t] += v;
            __syncthreads();
        }
        int run = red[t] - tot;
        for (int j = 0; j < 8; ++j) { basev[base + j] = run; run += loc[j]; }
    }
    __syncthreads();
    for (int i = t; i < MAXB; i += 256) hist[i] = 0;
    __syncthreads();
    for (int k = 0; k < PCH / 256; ++k) {
        int i = t + k * 256;
        if (i < cntE) {
            int s = src[lo + i], d = dst[lo + i];
            int bk = d >> BSH;
            int pos = basev[bk] + atomicAdd(&hist[bk], 1);
            pk[pos]  = (s << BSH) | (d & (BKT - 1));
            bkl[pos] = (unsigned short)bk;
        }
    }
    __syncthreads();
    for (int i = t; i < MAXB; i += 256) { int c = hist[i]; gb[i] = c ? atomicAdd(&cur[i], c) : 0; }
    __syncthreads();
    for (int i = t; i < cntE; i += 256) {
        int bk = bkl[i];
        st[gb[bk] + (i - basev[bk])] = pk[i];
    }
}

// ---------- per-dst degree from staged bucket lists --------------------------
__global__ void k_dhist2(const int* __restrict__ gsA, const int* __restrict__ stA,
                         int* __restrict__ cntA, int nA, int nbA,
                         const int* __restrict__ gsB, const int* __restrict__ stB,
                         int* __restrict__ cntB, int nB) {
    __shared__ int h[BKT];
    int b = blockIdx.x;
    const int* gs; const int* st; int* cnt; int n; int bb;
    if (b < nbA) { gs = gsA; st = stA; cnt = cntA; n = nA; bb = b; }
    else         { gs = gsB; st = stB; cnt = cntB; n = nB; bb = b - nbA; }
    int t = threadIdx.x;
    if (t < BKT) h[t] = 0;
    __syncthreads();
    int s0 = gs[bb], s1 = gs[bb + 1];
    for (int i = s0 + t; i < s1; i += 256) atomicAdd(&h[st[i] & (BKT - 1)], 1);
    __syncthreads();
    if (t < BKT) { int v = bb * BKT + t; if (v < n) cnt[v] = h[t]; }
}

// ---------- scan passes over per-dst counts -> rowptr ------------------------
__global__ void k_scan_partial(const int* __restrict__ cntA, int nA,
                               const int* __restrict__ cntB, int nB,
                               int* __restrict__ tsum, int* __restrict__ bsum) {
    __shared__ int red[NT];
    int sel = blockIdx.x / NB;
    int b   = blockIdx.x % NB;
    const int* cnt = sel ? cntB : cntA;
    int n = sel ? nB : nA;
    int sub = (n + NB * NT - 1) / (NB * NT);
    int t = threadIdx.x;
    int gt = b * NT + t;
    long long lo = (long long)gt * sub;
    int s = 0;
    for (int i = 0; i < sub; ++i) {
        long long idx = lo + i;
        if (idx < n) s += cnt[idx];
    }
    tsum[(size_t)sel * NB * NT + gt] = s;
    red[t] = s;
    __syncthreads();
    for (int off = NT / 2; off > 0; off >>= 1) {
        if (t < off) red[t] += red[t + off];
        __syncthreads();
    }
    if (t == 0) bsum[sel * NB + b] = red[0];
}

__global__ void k_scan_bsum(int* __restrict__ bsum) {
    __shared__ int sh[NB];
    int t = threadIdx.x;
    for (int sel = 0; sel < 2; ++sel) {
        int v = bsum[sel * NB + t];
        sh[t] = v;
        __syncthreads();
        for (int off = 1; off < NB; off <<= 1) {
            int u = (t >= off) ? sh[t - off] : 0;
            __syncthreads();
            sh[t] += u;
            __syncthreads();
        }
        bsum[sel * NB + t] = sh[t] - v;
        __syncthreads();
    }
}

__global__ void k_scan_write(const int* __restrict__ cntA, int nA, int* __restrict__ rpA,
                             const int* __restrict__ cntB, int nB, int* __restrict__ rpB,
                             const int* __restrict__ tsum, const int* __restrict__ bsum) {
    __shared__ int sh[NT];
    int sel = blockIdx.x / NB;
    int b   = blockIdx.x % NB;
    const int* cnt = sel ? cntB : cntA;
    int* rp = sel ? rpB : rpA;
    int n = sel ? nB : nA;
    int sub = (n + NB * NT - 1) / (NB * NT);
    int t = threadIdx.x;
    int gt = b * NT + t;
    int v = tsum[(size_t)sel * NB * NT + gt];
    sh[t] = v;
    __syncthreads();
    for (int off = 1; off < NT; off <<= 1) {
        int u = (t >= off) ? sh[t - off] : 0;
        __syncthreads();
        sh[t] += u;
        __syncthreads();
    }
    int base = bsum[sel * NB + b] + sh[t] - v;
    long long lo = (long long)gt * sub;
    long long hi = lo + sub; if (hi > n) hi = n;
    for (long long i = lo; i < hi; ++i) { int c = cnt[i]; rp[i] = base; base += c; }
    if (lo < n && hi == n) rp[n] = base;
}

// ---------- in-place bucket sort: staged (bucket-grouped) -> exact CSR -------
__global__ __launch_bounds__(256) void k_bsort2(
        const int* __restrict__ gsA, const int* __restrict__ rpA, int* __restrict__ csrA,
        int nA, int nbA,
        const int* __restrict__ gsB, const int* __restrict__ rpB, int* __restrict__ csrB,
        int nB) {
    __shared__ int buf[SORTCAP];
    __shared__ int cur[BKT];
    int b = blockIdx.x;
    const int* gs; const int* rp; int* csr; int n; int bb;
    if (b < nbA) { gs = gsA; rp = rpA; csr = csrA; n = nA; bb = b; }
    else         { gs = gsB; rp = rpB; csr = csrB; n = nB; bb = b - nbA; }
    int t = threadIdx.x;
    int s0 = gs[bb], s1 = gs[bb + 1];
    int cnt = s1 - s0;
    for (int i = t; i < cnt; i += 256) buf[i] = csr[s0 + i];
    if (t < BKT) { int v = bb * BKT + t; cur[t] = (v < n) ? rp[v] : 0; }
    __syncthreads();
    for (int i = t; i < cnt; i += 256) {
        int p = buf[i];
        int pos = atomicAdd(&cur[p & (BKT - 1)], 1);
        csr[pos] = p >> BSH;
    }
}

// ---------- fused: out[v] = relu?( xdst[v]@Ws^T + b + mean gather @ Wn^T ) ----
// 8 nodes/block, 32 lanes/node. Gather: lanes = 4 edges x 8 float4-quarters.
// GEMM: weights in VGPRs (lane d holds Ws/Wn row d); x & mean staged once in
// LDS and read back as 16 broadcast ds_read_b128 per node (was 128 b32 reads).
__global__ __launch_bounds__(256) void k_fused(
        const float* __restrict__ xsrc, const float* __restrict__ xdst,
        const int* __restrict__ rowptr, const int* __restrict__ csr_src,
        const float* __restrict__ Ws, const float* __restrict__ Wn,
        const float* __restrict__ b,
        float* __restrict__ out, int n, int do_relu) {
    __shared__ float xm[8][2 * DD];   // [g][0..31]=x row, [g][32..63]=mean row
    int tid = threadIdx.x;
    int g = tid >> 5;
    int d = tid & 31;
    int v = blockIdx.x * 8 + g;

    if (v < n) {
        int rs = rowptr[v], re = rowptr[v + 1];
        int el = d >> 3;   // edge slot 0..3
        int q  = d & 7;    // float4 quarter 0..7
        float ax = 0.f, ay = 0.f, az = 0.f, aw = 0.f;
        for (int j0 = rs; j0 < re; j0 += 32) {
            int nj = re - j0; if (nj > 32) nj = 32;
            int myi = (d < nj) ? csr_src[j0 + d] : 0;
            for (int c0 = 0; c0 < nj; c0 += 4) {
                int jj = c0 + el;
                int s = __shfl(myi, jj, 32);
                if (jj < nj) {
                    const float4* row = (const float4*)(xsrc + (size_t)s * DD);
                    float4 x4 = row[q];
                    ax += x4.x; ay += x4.y; az += x4.z; aw += x4.w;
                }
            }
        }
        ax += __shfl_xor(ax, 8, 32);  ay += __shfl_xor(ay, 8, 32);
        az += __shfl_xor(az, 8, 32);  aw += __shfl_xor(aw, 8, 32);
        ax += __shfl_xor(ax, 16, 32); ay += __shfl_xor(ay, 16, 32);
        az += __shfl_xor(az, 16, 32); aw += __shfl_xor(aw, 16, 32);
        float degf = (float)(re - rs);
        float rinv = 1.0f / fmaxf(degf, 1.0f);
        if (el == 0) {
            float4 m4; m4.x = ax * rinv; m4.y = ay * rinv; m4.z = az * rinv; m4.w = aw * rinv;
            *(float4*)(&xm[g][DD + q * 4]) = m4;
        }
        xm[g][d] = xdst[(size_t)v * DD + d];
    }

    // weight rows into registers (statically indexed -> VGPRs)
    float4 cs[8], cn[8];
#pragma unroll
    for (int k4 = 0; k4 < 8; ++k4) {
        cs[k4] = *(const float4*)(Ws + d * DD + k4 * 4);
        cn[k4] = *(const float4*)(Wn + d * DD + k4 * 4);
    }
    float bv = b[d];

    __syncthreads();
    if (v < n) {
        float s2 = bv;
#pragma unroll
        for (int k4 = 0; k4 < 8; ++k4) {
            float4 xv = *(const float4*)(&xm[g][k4 * 4]);        // broadcast read
            float4 mv = *(const float4*)(&xm[g][DD + k4 * 4]);   // broadcast read
            s2 += xv.x * cs[k4].x + xv.y * cs[k4].y + xv.z * cs[k4].z + xv.w * cs[k4].w;
            s2 += mv.x * cn[k4].x + mv.y * cn[k4].y + mv.z * cn[k4].z + mv.w * cn[k4].w;
        }
        if (do_relu) s2 = fmaxf(s2, 0.f);
        out[(size_t)v * DD + d] = s2;
    }
}

extern "C" void kernel_launch(void* const* d_in, const int* in_sizes, int n_in,
                              void* d_out, int out_size, void* d_ws, size_t ws_size,
                              hipStream_t stream) {
    const float* x_user = (const float*)d_in[0];
    const float* x_item = (const float*)d_in[1];
    const int*   ui_src = (const int*)d_in[2];
    const int*   ui_dst = (const int*)d_in[3];
    const int*   iu_src = (const int*)d_in[4];
    const int*   iu_dst = (const int*)d_in[5];
    const float* Ws_ui1 = (const float*)d_in[6];
    const float* Wn_ui1 = (const float*)d_in[7];
    const float* Ws_iu1 = (const float*)d_in[8];
    const float* Wn_iu1 = (const float*)d_in[9];
    const float* Ws_ui2 = (const float*)d_in[10];
    const float* Wn_ui2 = (const float*)d_in[11];
    const float* Ws_iu2 = (const float*)d_in[12];
    const float* Wn_iu2 = (const float*)d_in[13];
    const float* b_ui1  = (const float*)d_in[14];
    const float* b_iu1  = (const float*)d_in[15];
    const float* b_ui2  = (const float*)d_in[16];
    const float* b_iu2  = (const float*)d_in[17];

    int NU = in_sizes[0] / DD;
    int NI = in_sizes[1] / DD;
    int E  = in_sizes[2];
    int NBI = (NI + BKT - 1) >> BSH;
    int NBU = (NU + BKT - 1) >> BSH;
    int NMAX = (NU > NI) ? NU : NI;

    // ---- persistent workspace ----
    char* wp = (char*)d_ws;
    float* O_item = (float*)wp;  wp += (size_t)NI * DD * sizeof(float);
    int* csr_ui   = (int*)wp;    wp += (size_t)E * sizeof(int);
    int* csr_iu   = (int*)wp;    wp += (size_t)E * sizeof(int);
    int* rp_item  = (int*)wp;    wp += (size_t)(NI + 1) * sizeof(int);
    int* rp_user  = (int*)wp;

    // ---- transient arrays alias O_item (dead until layer 2) ----
    int* tr = (int*)O_item;
    int* bcntI = tr;  tr += MAXB;
    int* bcntU = tr;  tr += MAXB;
    int* gsI   = tr;  tr += MAXB + 1;
    int* gsU   = tr;  tr += MAXB + 1;
    int* curI  = tr;  tr += MAXB;
    int* curU  = tr;  tr += MAXB;
    int* cntI  = tr;  tr += NMAX;
    int* cntU  = tr;  tr += NMAX;
    int* tsum  = tr;  tr += 2 * NB * NT;
    int* bsum  = tr;

    float* h_user = (float*)d_out;
    float* h_item = h_user + (size_t)NU * DD;

    int EB = (E + PCH - 1) / PCH;

    // ---- CSR build: bucket partition -> per-dst counts -> scan -> local sort
    (void)hipMemsetAsync(bcntI, 0, (size_t)2 * MAXB * sizeof(int), stream);
    hipLaunchKernelGGL(k_bhist, dim3(2 * EB), dim3(256), 0, stream,
                       ui_dst, bcntI, iu_dst, bcntU, E, EB);
    hipLaunchKernelGGL(k_bscan, dim3(1), dim3(256), 0, stream,
                       bcntI, gsI, curI, NBI, bcntU, gsU, curU, NBU);
    hipLaunchKernelGGL(k_part, dim3(2 * EB), dim3(256), 0, stream,
                       ui_src, ui_dst, curI, csr_ui,
                       iu_src, iu_dst, curU, csr_iu, E, EB);
    hipLaunchKernelGGL(k_dhist2, dim3(NBI + NBU), dim3(256), 0, stream,
                       gsI, csr_ui, cntI, NI, NBI, gsU, csr_iu, cntU, NU);
    hipLaunchKernelGGL(k_scan_partial, dim3(2 * NB), dim3(NT), 0, stream,
                       cntI, NI, cntU, NU, tsum, bsum);
    hipLaunchKernelGGL(k_scan_bsum, dim3(1), dim3(NB), 0, stream, bsum);
    hipLaunchKernelGGL(k_scan_write, dim3(2 * NB), dim3(NT), 0, stream,
                       cntI, NI, rp_item, cntU, NU, rp_user, tsum, bsum);
    hipLaunchKernelGGL(k_bsort2, dim3(NBI + NBU), dim3(256), 0, stream,
                       gsI, rp_item, csr_ui, NI, NBI, gsU, rp_user, csr_iu, NU);

    // ---- layer 1 (relu) ----
    hipLaunchKernelGGL(k_fused, dim3((NI + 7) / 8), dim3(256), 0, stream,
                       x_user, x_item, rp_item, csr_ui, Ws_ui1, Wn_ui1, b_ui1,
                       h_item, NI, 1);
    hipLaunchKernelGGL(k_fused, dim3((NU + 7) / 8), dim3(256), 0, stream,
                       x_item, x_user, rp_user, csr_iu, Ws_iu1, Wn_iu1, b_iu1,
                       h_user, NU, 1);

    // ---- layer 2 (no relu) ----
    hipLaunchKernelGGL(k_fused, dim3((NI + 7) / 8), dim3(256), 0, stream,
                       h_user, h_item, rp_item, csr_ui, Ws_ui2, Wn_ui2, b_ui2,
                       O_item, NI, 0);
    hipLaunchKernelGGL(k_fused, dim3((NU + 7) / 8), dim3(256), 0, stream,
                       h_item, h_user, rp_user, csr_iu, Ws_iu2, Wn_iu2, b_iu2,
                       h_user, NU, 0);

    (void)hipMemcpyAsync(h_item, O_item, (size_t)NI * DD * sizeof(float),
                         hipMemcpyDeviceToDevice, stream);
}

// Round 8
// 435.068 us; speedup vs baseline: 2.3904x; 2.3904x over previous
//
#include <hip/hip_runtime.h>

#define DD   32
#define WP   33       // padded stride for transposed weights (bank-conflict-free)
#define BKT  128      // dsts per bucket (power of two)
#define BSH  7        // log2(BKT)
#define PCH  4096     // edges per partition/hist block
#define MAXB 2048     // padded bucket-count (>= nbkt)
#define NB   256      // scan blocks per array
#define NT   256      // scan threads per block
#define SORTCAP 8192  // max edges per bucket for in-place sort (mean ~1280)

// ---------- bucket histogram (both relations, LDS pre-aggregated) ------------
__global__ void k_bhist(const int* __restrict__ dstA, int* __restrict__ cntA,
                        const int* __restrict__ dstB, int* __restrict__ cntB,
                        int E, int blocksPer) {
    __shared__ int h[MAXB];
    int b = blockIdx.x;
    const int* dst = (b < blocksPer) ? dstA : dstB;
    int* cnt       = (b < blocksPer) ? cntA : cntB;
    int bb         = (b < blocksPer) ? b : b - blocksPer;
    int t = threadIdx.x;
    for (int i = t; i < MAXB; i += 256) h[i] = 0;
    __syncthreads();
    int lo = bb * PCH;
    for (int k = 0; k < PCH / 256; ++k) {
        int i = lo + t + k * 256;
        if (i < E) atomicAdd(&h[dst[i] >> BSH], 1);
    }
    __syncthreads();
    for (int i = t; i < MAXB; i += 256) { int c = h[i]; if (c) atomicAdd(&cnt[i], c); }
}

// ---------- scan bucket counts -> gscan[nbkt+1] and cursor copy --------------
__global__ void k_bscan(const int* __restrict__ cntA, int* __restrict__ gsA, int* __restrict__ curA, int nbktA,
                        const int* __restrict__ cntB, int* __restrict__ gsB, int* __restrict__ curB, int nbktB) {
    __shared__ int sh[MAXB];
    __shared__ int red[256];
    int t = threadIdx.x;
    for (int sel = 0; sel < 2; ++sel) {
        const int* cnt = sel ? cntB : cntA;
        int* gs  = sel ? gsB : gsA;
        int* cur = sel ? curB : curA;
        int nbkt = sel ? nbktB : nbktA;
        for (int i = t; i < MAXB; i += 256) sh[i] = (i < nbkt) ? cnt[i] : 0;
        __syncthreads();
        int base = t * 8;
        int loc[8]; int tot = 0;
        for (int j = 0; j < 8; ++j) { loc[j] = sh[base + j]; tot += loc[j]; }
        red[t] = tot;
        __syncthreads();
        for (int off = 1; off < 256; off <<= 1) {
            int v = (t >= off) ? red[t - off] : 0;
            __syncthreads();
            red[t] += v;
            __syncthreads();
        }
        int run = red[t] - tot;
        for (int j = 0; j < 8; ++j) { sh[base + j] = run; run += loc[j]; }
        __syncthreads();
        for (int i = t; i < nbkt; i += 256) { gs[i] = sh[i]; cur[i] = sh[i]; }
        if (t == 255) gs[nbkt] = red[255];
        __syncthreads();
    }
}

// ---------- partition: staged[pos] = (src<<BSH) | (dst & (BKT-1)) ------------
__global__ void k_part(const int* __restrict__ srcA, const int* __restrict__ dstA,
                       int* __restrict__ curA, int* __restrict__ stA,
                       const int* __restrict__ srcB, const int* __restrict__ dstB,
                       int* __restrict__ curB, int* __restrict__ stB,
                       int E, int blocksPer) {
    __shared__ int pk[PCH];
    __shared__ unsigned short bkl[PCH];
    __shared__ int hist[MAXB];
    __shared__ int basev[MAXB];
    __shared__ int gb[MAXB];
    __shared__ int red[256];
    int b = blockIdx.x;
    const int* src; const int* dst; int* cur; int* st; int bb;
    if (b < blocksPer) { src = srcA; dst = dstA; cur = curA; st = stA; bb = b; }
    else               { src = srcB; dst = dstB; cur = curB; st = stB; bb = b - blocksPer; }
    int t = threadIdx.x;
    int lo = bb * PCH;
    int cntE = E - lo; if (cntE > PCH) cntE = PCH;

    for (int i = t; i < MAXB; i += 256) hist[i] = 0;
    __syncthreads();
    for (int k = 0; k < PCH / 256; ++k) {
        int i = t + k * 256;
        if (i < cntE) atomicAdd(&hist[dst[lo + i] >> BSH], 1);
    }
    __syncthreads();
    {
        int base = t * 8;
        int loc[8]; int tot = 0;
        for (int j = 0; j < 8; ++j) { loc[j] = hist[base + j]; tot += loc[j]; }
        red[t] = tot;
        __syncthreads();
        for (int off = 1; off < 256; off <<= 1) {
            int v = (t >= off) ? red[t - off] : 0;
            __syncthreads();
            red[t] += v;
            __syncthreads();
        }
        int run = red[t] - tot;
        for (int j = 0; j < 8; ++j) { basev[base + j] = run; run += loc[j]; }
    }
    __syncthreads();
    for (int i = t; i < MAXB; i += 256) hist[i] = 0;
    __syncthreads();
    for (int k = 0; k < PCH / 256; ++k) {
        int i = t + k * 256;
        if (i < cntE) {
            int s = src[lo + i], d = dst[lo + i];
            int bk = d >> BSH;
            int pos = basev[bk] + atomicAdd(&hist[bk], 1);
            pk[pos]  = (s << BSH) | (d & (BKT - 1));
            bkl[pos] = (unsigned short)bk;
        }
    }
    __syncthreads();
    for (int i = t; i < MAXB; i += 256) { int c = hist[i]; gb[i] = c ? atomicAdd(&cur[i], c) : 0; }
    __syncthreads();
    for (int i = t; i < cntE; i += 256) {
        int bk = bkl[i];
        st[gb[bk] + (i - basev[bk])] = pk[i];
    }
}

// ---------- per-dst degree from staged bucket lists --------------------------
__global__ void k_dhist2(const int* __restrict__ gsA, const int* __restrict__ stA,
                         int* __restrict__ cntA, int nA, int nbA,
                         const int* __restrict__ gsB, const int* __restrict__ stB,
                         int* __restrict__ cntB, int nB) {
    __shared__ int h[BKT];
    int b = blockIdx.x;
    const int* gs; const int* st; int* cnt; int n; int bb;
    if (b < nbA) { gs = gsA; st = stA; cnt = cntA; n = nA; bb = b; }
    else         { gs = gsB; st = stB; cnt = cntB; n = nB; bb = b - nbA; }
    int t = threadIdx.x;
    if (t < BKT) h[t] = 0;
    __syncthreads();
    int s0 = gs[bb], s1 = gs[bb + 1];
    for (int i = s0 + t; i < s1; i += 256) atomicAdd(&h[st[i] & (BKT - 1)], 1);
    __syncthreads();
    if (t < BKT) { int v = bb * BKT + t; if (v < n) cnt[v] = h[t]; }
}

// ---------- scan passes over per-dst counts -> rowptr ------------------------
__global__ void k_scan_partial(const int* __restrict__ cntA, int nA,
                               const int* __restrict__ cntB, int nB,
                               int* __restrict__ tsum, int* __restrict__ bsum) {
    __shared__ int red[NT];
    int sel = blockIdx.x / NB;
    int b   = blockIdx.x % NB;
    const int* cnt = sel ? cntB : cntA;
    int n = sel ? nB : nA;
    int sub = (n + NB * NT - 1) / (NB * NT);
    int t = threadIdx.x;
    int gt = b * NT + t;
    long long lo = (long long)gt * sub;
    int s = 0;
    for (int i = 0; i < sub; ++i) {
        long long idx = lo + i;
        if (idx < n) s += cnt[idx];
    }
    tsum[(size_t)sel * NB * NT + gt] = s;
    red[t] = s;
    __syncthreads();
    for (int off = NT / 2; off > 0; off >>= 1) {
        if (t < off) red[t] += red[t + off];
        __syncthreads();
    }
    if (t == 0) bsum[sel * NB + b] = red[0];
}

__global__ void k_scan_bsum(int* __restrict__ bsum) {
    __shared__ int sh[NB];
    int t = threadIdx.x;
    for (int sel = 0; sel < 2; ++sel) {
        int v = bsum[sel * NB + t];
        sh[t] = v;
        __syncthreads();
        for (int off = 1; off < NB; off <<= 1) {
            int u = (t >= off) ? sh[t - off] : 0;
            __syncthreads();
            sh[t] += u;
            __syncthreads();
        }
        bsum[sel * NB + t] = sh[t] - v;
        __syncthreads();
    }
}

__global__ void k_scan_write(const int* __restrict__ cntA, int nA, int* __restrict__ rpA,
                             const int* __restrict__ cntB, int nB, int* __restrict__ rpB,
                             const int* __restrict__ tsum, const int* __restrict__ bsum) {
    __shared__ int sh[NT];
    int sel = blockIdx.x / NB;
    int b   = blockIdx.x % NB;
    const int* cnt = sel ? cntB : cntA;
    int* rp = sel ? rpB : rpA;
    int n = sel ? nB : nA;
    int sub = (n + NB * NT - 1) / (NB * NT);
    int t = threadIdx.x;
    int gt = b * NT + t;
    int v = tsum[(size_t)sel * NB * NT + gt];
    sh[t] = v;
    __syncthreads();
    for (int off = 1; off < NT; off <<= 1) {
        int u = (t >= off) ? sh[t - off] : 0;
        __syncthreads();
        sh[t] += u;
        __syncthreads();
    }
    int base = bsum[sel * NB + b] + sh[t] - v;
    long long lo = (long long)gt * sub;
    long long hi = lo + sub; if (hi > n) hi = n;
    for (long long i = lo; i < hi; ++i) { int c = cnt[i]; rp[i] = base; base += c; }
    if (lo < n && hi == n) rp[n] = base;
}

// ---------- in-place bucket sort: staged (bucket-grouped) -> exact CSR -------
__global__ __launch_bounds__(256) void k_bsort2(
        const int* __restrict__ gsA, const int* __restrict__ rpA, int* __restrict__ csrA,
        int nA, int nbA,
        const int* __restrict__ gsB, const int* __restrict__ rpB, int* __restrict__ csrB,
        int nB) {
    __shared__ int buf[SORTCAP];
    __shared__ int cur[BKT];
    int b = blockIdx.x;
    const int* gs; const int* rp; int* csr; int n; int bb;
    if (b < nbA) { gs = gsA; rp = rpA; csr = csrA; n = nA; bb = b; }
    else         { gs = gsB; rp = rpB; csr = csrB; n = nB; bb = b - nbA; }
    int t = threadIdx.x;
    int s0 = gs[bb], s1 = gs[bb + 1];
    int cnt = s1 - s0;
    for (int i = t; i < cnt; i += 256) buf[i] = csr[s0 + i];
    if (t < BKT) { int v = bb * BKT + t; cur[t] = (v < n) ? rp[v] : 0; }
    __syncthreads();
    for (int i = t; i < cnt; i += 256) {
        int p = buf[i];
        int pos = atomicAdd(&cur[p & (BKT - 1)], 1);
        csr[pos] = p >> BSH;
    }
}

// ---------- fused: out[v] = relu?( xdst[v]@Ws^T + b + mean gather @ Wn^T ) ----
// R6 structure (weights transposed in LDS) with stride-33 pad: transpose STORE
// WsT[c*WP+r] puts lanes in banks (c+r)%32 (all distinct) and GEMM READ
// WsT[k*WP+d] in banks (k+d)%32 (all distinct) -> zero bank conflicts.
__global__ void k_fused(const float* __restrict__ xsrc, const float* __restrict__ xdst,
                        const int* __restrict__ rowptr, const int* __restrict__ csr_src,
                        const float* __restrict__ Ws, const float* __restrict__ Wn,
                        const float* __restrict__ b,
                        float* __restrict__ out, int n, int do_relu) {
    __shared__ float WsT[DD * WP], WnT[DD * WP], bsh[DD];
    __shared__ float xrow[8][DD], mrow[8][DD];
    int tid = threadIdx.x;
    for (int i = tid; i < DD * DD; i += 256) {
        int r = i >> 5, c = i & 31;
        WsT[c * WP + r] = Ws[i];
        WnT[c * WP + r] = Wn[i];
    }
    if (tid < DD) bsh[tid] = b[tid];
    int g = tid >> 5;
    int d = tid & 31;
    int v = blockIdx.x * 8 + g;
    if (v < n) {
        int rs = rowptr[v], re = rowptr[v + 1];
        int el = d >> 3;   // edge slot 0..3
        int q  = d & 7;    // float4 quarter 0..7
        float ax = 0.f, ay = 0.f, az = 0.f, aw = 0.f;
        for (int j0 = rs; j0 < re; j0 += 32) {
            int nj = re - j0; if (nj > 32) nj = 32;
            int myi = (d < nj) ? csr_src[j0 + d] : 0;
            for (int c0 = 0; c0 < nj; c0 += 4) {
                int jj = c0 + el;
                int s = __shfl(myi, jj, 32);
                if (jj < nj) {
                    const float4* row = (const float4*)(xsrc + (size_t)s * DD);
                    float4 x4 = row[q];
                    ax += x4.x; ay += x4.y; az += x4.z; aw += x4.w;
                }
            }
        }
        ax += __shfl_xor(ax, 8, 32);  ay += __shfl_xor(ay, 8, 32);
        az += __shfl_xor(az, 8, 32);  aw += __shfl_xor(aw, 8, 32);
        ax += __shfl_xor(ax, 16, 32); ay += __shfl_xor(ay, 16, 32);
        az += __shfl_xor(az, 16, 32); aw += __shfl_xor(aw, 16, 32);
        float degf = (float)(re - rs);
        float rinv = 1.0f / fmaxf(degf, 1.0f);
        if (el == 0) {
            float4 m4; m4.x = ax * rinv; m4.y = ay * rinv; m4.z = az * rinv; m4.w = aw * rinv;
            ((float4*)(&mrow[g][0]))[q] = m4;
        }
        xrow[g][d] = xdst[(size_t)v * DD + d];
    }
    __syncthreads();
    if (v < n) {
        float s2 = bsh[d];
#pragma unroll
        for (int k = 0; k < DD; ++k) {
            s2 += xrow[g][k] * WsT[k * WP + d] + mrow[g][k] * WnT[k * WP + d];
        }
        if (do_relu) s2 = fmaxf(s2, 0.f);
        out[(size_t)v * DD + d] = s2;
    }
}

extern "C" void kernel_launch(void* const* d_in, const int* in_sizes, int n_in,
                              void* d_out, int out_size, void* d_ws, size_t ws_size,
                              hipStream_t stream) {
    const float* x_user = (const float*)d_in[0];
    const float* x_item = (const float*)d_in[1];
    const int*   ui_src = (const int*)d_in[2];
    const int*   ui_dst = (const int*)d_in[3];
    const int*   iu_src = (const int*)d_in[4];
    const int*   iu_dst = (const int*)d_in[5];
    const float* Ws_ui1 = (const float*)d_in[6];
    const float* Wn_ui1 = (const float*)d_in[7];
    const float* Ws_iu1 = (const float*)d_in[8];
    const float* Wn_iu1 = (const float*)d_in[9];
    const float* Ws_ui2 = (const float*)d_in[10];
    const float* Wn_ui2 = (const float*)d_in[11];
    const float* Ws_iu2 = (const float*)d_in[12];
    const float* Wn_iu2 = (const float*)d_in[13];
    const float* b_ui1  = (const float*)d_in[14];
    const float* b_iu1  = (const float*)d_in[15];
    const float* b_ui2  = (const float*)d_in[16];
    const float* b_iu2  = (const float*)d_in[17];

    int NU = in_sizes[0] / DD;
    int NI = in_sizes[1] / DD;
    int E  = in_sizes[2];
    int NBI = (NI + BKT - 1) >> BSH;
    int NBU = (NU + BKT - 1) >> BSH;
    int NMAX = (NU > NI) ? NU : NI;

    // ---- persistent workspace ----
    char* wp = (char*)d_ws;
    float* O_item = (float*)wp;  wp += (size_t)NI * DD * sizeof(float);
    int* csr_ui   = (int*)wp;    wp += (size_t)E * sizeof(int);
    int* csr_iu   = (int*)wp;    wp += (size_t)E * sizeof(int);
    int* rp_item  = (int*)wp;    wp += (size_t)(NI + 1) * sizeof(int);
    int* rp_user  = (int*)wp;

    // ---- transient arrays alias O_item (dead until layer 2) ----
    int* tr = (int*)O_item;
    int* bcntI = tr;  tr += MAXB;
    int* bcntU = tr;  tr += MAXB;
    int* gsI   = tr;  tr += MAXB + 1;
    int* gsU   = tr;  tr += MAXB + 1;
    int* curI  = tr;  tr += MAXB;
    int* curU  = tr;  tr += MAXB;
    int* cntI  = tr;  tr += NMAX;
    int* cntU  = tr;  tr += NMAX;
    int* tsum  = tr;  tr += 2 * NB * NT;
    int* bsum  = tr;

    float* h_user = (float*)d_out;
    float* h_item = h_user + (size_t)NU * DD;

    int EB = (E + PCH - 1) / PCH;

    // ---- CSR build: bucket partition -> per-dst counts -> scan -> local sort
    (void)hipMemsetAsync(bcntI, 0, (size_t)2 * MAXB * sizeof(int), stream);
    hipLaunchKernelGGL(k_bhist, dim3(2 * EB), dim3(256), 0, stream,
                       ui_dst, bcntI, iu_dst, bcntU, E, EB);
    hipLaunchKernelGGL(k_bscan, dim3(1), dim3(256), 0, stream,
                       bcntI, gsI, curI, NBI, bcntU, gsU, curU, NBU);
    hipLaunchKernelGGL(k_part, dim3(2 * EB), dim3(256), 0, stream,
                       ui_src, ui_dst, curI, csr_ui,
                       iu_src, iu_dst, curU, csr_iu, E, EB);
    hipLaunchKernelGGL(k_dhist2, dim3(NBI + NBU), dim3(256), 0, stream,
                       gsI, csr_ui, cntI, NI, NBI, gsU, csr_iu, cntU, NU);
    hipLaunchKernelGGL(k_scan_partial, dim3(2 * NB), dim3(NT), 0, stream,
                       cntI, NI, cntU, NU, tsum, bsum);
    hipLaunchKernelGGL(k_scan_bsum, dim3(1), dim3(NB), 0, stream, bsum);
    hipLaunchKernelGGL(k_scan_write, dim3(2 * NB), dim3(NT), 0, stream,
                       cntI, NI, rp_item, cntU, NU, rp_user, tsum, bsum);
    hipLaunchKernelGGL(k_bsort2, dim3(NBI + NBU), dim3(256), 0, stream,
                       gsI, rp_item, csr_ui, NI, NBI, gsU, rp_user, csr_iu, NU);

    // ---- layer 1 (relu) ----
    hipLaunchKernelGGL(k_fused, dim3((NI + 7) / 8), dim3(256), 0, stream,
                       x_user, x_item, rp_item, csr_ui, Ws_ui1, Wn_ui1, b_ui1,
                       h_item, NI, 1);
    hipLaunchKernelGGL(k_fused, dim3((NU + 7) / 8), dim3(256), 0, stream,
                       x_item, x_user, rp_user, csr_iu, Ws_iu1, Wn_iu1, b_iu1,
                       h_user, NU, 1);

    // ---- layer 2 (no relu) ----
    hipLaunchKernelGGL(k_fused, dim3((NI + 7) / 8), dim3(256), 0, stream,
                       h_user, h_item, rp_item, csr_ui, Ws_ui2, Wn_ui2, b_ui2,
                       O_item, NI, 0);
    hipLaunchKernelGGL(k_fused, dim3((NU + 7) / 8), dim3(256), 0, stream,
                       h_item, h_user, rp_user, csr_iu, Ws_iu2, Wn_iu2, b_iu2,
                       h_user, NU, 0);

    (void)hipMemcpyAsync(h_item, O_item, (size_t)NI * DD * sizeof(float),
                         hipMemcpyDeviceToDevice, stream);
}

// Round 9
// 423.404 us; speedup vs baseline: 2.4562x; 1.0275x over previous
//
#include <hip/hip_runtime.h>

#define DD   32
#define WP   33       // padded stride for transposed weights (bank-conflict-free)
#define BKT  128      // dsts per bucket (power of two)
#define BSH  7        // log2(BKT)
#define PCH  4096     // edges per partition/hist block
#define MAXB 2048     // padded bucket-count (>= nbkt)
#define NB   256      // scan blocks per array
#define NT   256      // scan threads per block
#define SORTCAP 8192  // max edges per bucket for in-place sort (mean ~1280)

// ---------- bucket histogram (both relations, LDS pre-aggregated) ------------
__global__ void k_bhist(const int* __restrict__ dstA, int* __restrict__ cntA,
                        const int* __restrict__ dstB, int* __restrict__ cntB,
                        int E, int blocksPer) {
    __shared__ int h[MAXB];
    int b = blockIdx.x;
    const int* dst = (b < blocksPer) ? dstA : dstB;
    int* cnt       = (b < blocksPer) ? cntA : cntB;
    int bb         = (b < blocksPer) ? b : b - blocksPer;
    int t = threadIdx.x;
    for (int i = t; i < MAXB; i += 256) h[i] = 0;
    __syncthreads();
    int lo = bb * PCH;
    for (int k = 0; k < PCH / 256; ++k) {
        int i = lo + t + k * 256;
        if (i < E) atomicAdd(&h[dst[i] >> BSH], 1);
    }
    __syncthreads();
    for (int i = t; i < MAXB; i += 256) { int c = h[i]; if (c) atomicAdd(&cnt[i], c); }
}

// ---------- scan bucket counts -> gscan[nbkt+1] and cursor copy --------------
__global__ void k_bscan(const int* __restrict__ cntA, int* __restrict__ gsA, int* __restrict__ curA, int nbktA,
                        const int* __restrict__ cntB, int* __restrict__ gsB, int* __restrict__ curB, int nbktB) {
    __shared__ int sh[MAXB];
    __shared__ int red[256];
    int t = threadIdx.x;
    for (int sel = 0; sel < 2; ++sel) {
        const int* cnt = sel ? cntB : cntA;
        int* gs  = sel ? gsB : gsA;
        int* cur = sel ? curB : curA;
        int nbkt = sel ? nbktB : nbktA;
        for (int i = t; i < MAXB; i += 256) sh[i] = (i < nbkt) ? cnt[i] : 0;
        __syncthreads();
        int base = t * 8;
        int loc[8]; int tot = 0;
        for (int j = 0; j < 8; ++j) { loc[j] = sh[base + j]; tot += loc[j]; }
        red[t] = tot;
        __syncthreads();
        for (int off = 1; off < 256; off <<= 1) {
            int v = (t >= off) ? red[t - off] : 0;
            __syncthreads();
            red[t] += v;
            __syncthreads();
        }
        int run = red[t] - tot;
        for (int j = 0; j < 8; ++j) { sh[base + j] = run; run += loc[j]; }
        __syncthreads();
        for (int i = t; i < nbkt; i += 256) { gs[i] = sh[i]; cur[i] = sh[i]; }
        if (t == 255) gs[nbkt] = red[255];
        __syncthreads();
    }
}

// ---------- partition: staged[pos] = (src<<BSH) | (dst & (BKT-1)) ------------
__global__ void k_part(const int* __restrict__ srcA, const int* __restrict__ dstA,
                       int* __restrict__ curA, int* __restrict__ stA,
                       const int* __restrict__ srcB, const int* __restrict__ dstB,
                       int* __restrict__ curB, int* __restrict__ stB,
                       int E, int blocksPer) {
    __shared__ int pk[PCH];
    __shared__ unsigned short bkl[PCH];
    __shared__ int hist[MAXB];
    __shared__ int basev[MAXB];
    __shared__ int gb[MAXB];
    __shared__ int red[256];
    int b = blockIdx.x;
    const int* src; const int* dst; int* cur; int* st; int bb;
    if (b < blocksPer) { src = srcA; dst = dstA; cur = curA; st = stA; bb = b; }
    else               { src = srcB; dst = dstB; cur = curB; st = stB; bb = b - blocksPer; }
    int t = threadIdx.x;
    int lo = bb * PCH;
    int cntE = E - lo; if (cntE > PCH) cntE = PCH;

    for (int i = t; i < MAXB; i += 256) hist[i] = 0;
    __syncthreads();
    for (int k = 0; k < PCH / 256; ++k) {
        int i = t + k * 256;
        if (i < cntE) atomicAdd(&hist[dst[lo + i] >> BSH], 1);
    }
    __syncthreads();
    {
        int base = t * 8;
        int loc[8]; int tot = 0;
        for (int j = 0; j < 8; ++j) { loc[j] = hist[base + j]; tot += loc[j]; }
        red[t] = tot;
        __syncthreads();
        for (int off = 1; off < 256; off <<= 1) {
            int v = (t >= off) ? red[t - off] : 0;
            __syncthreads();
            red[t] += v;
            __syncthreads();
        }
        int run = red[t] - tot;
        for (int j = 0; j < 8; ++j) { basev[base + j] = run; run += loc[j]; }
    }
    __syncthreads();
    for (int i = t; i < MAXB; i += 256) hist[i] = 0;
    __syncthreads();
    for (int k = 0; k < PCH / 256; ++k) {
        int i = t + k * 256;
        if (i < cntE) {
            int s = src[lo + i], d = dst[lo + i];
            int bk = d >> BSH;
            int pos = basev[bk] + atomicAdd(&hist[bk], 1);
            pk[pos]  = (s << BSH) | (d & (BKT - 1));
            bkl[pos] = (unsigned short)bk;
        }
    }
    __syncthreads();
    for (int i = t; i < MAXB; i += 256) { int c = hist[i]; gb[i] = c ? atomicAdd(&cur[i], c) : 0; }
    __syncthreads();
    for (int i = t; i < cntE; i += 256) {
        int bk = bkl[i];
        st[gb[bk] + (i - basev[bk])] = pk[i];
    }
}

// ---------- per-dst degree from staged bucket lists --------------------------
__global__ void k_dhist2(const int* __restrict__ gsA, const int* __restrict__ stA,
                         int* __restrict__ cntA, int nA, int nbA,
                         const int* __restrict__ gsB, const int* __restrict__ stB,
                         int* __restrict__ cntB, int nB) {
    __shared__ int h[BKT];
    int b = blockIdx.x;
    const int* gs; const int* st; int* cnt; int n; int bb;
    if (b < nbA) { gs = gsA; st = stA; cnt = cntA; n = nA; bb = b; }
    else         { gs = gsB; st = stB; cnt = cntB; n = nB; bb = b - nbA; }
    int t = threadIdx.x;
    if (t < BKT) h[t] = 0;
    __syncthreads();
    int s0 = gs[bb], s1 = gs[bb + 1];
    for (int i = s0 + t; i < s1; i += 256) atomicAdd(&h[st[i] & (BKT - 1)], 1);
    __syncthreads();
    if (t < BKT) { int v = bb * BKT + t; if (v < n) cnt[v] = h[t]; }
}

// ---------- scan passes over per-dst counts -> rowptr ------------------------
__global__ void k_scan_partial(const int* __restrict__ cntA, int nA,
                               const int* __restrict__ cntB, int nB,
                               int* __restrict__ tsum, int* __restrict__ bsum) {
    __shared__ int red[NT];
    int sel = blockIdx.x / NB;
    int b   = blockIdx.x % NB;
    const int* cnt = sel ? cntB : cntA;
    int n = sel ? nB : nA;
    int sub = (n + NB * NT - 1) / (NB * NT);
    int t = threadIdx.x;
    int gt = b * NT + t;
    long long lo = (long long)gt * sub;
    int s = 0;
    for (int i = 0; i < sub; ++i) {
        long long idx = lo + i;
        if (idx < n) s += cnt[idx];
    }
    tsum[(size_t)sel * NB * NT + gt] = s;
    red[t] = s;
    __syncthreads();
    for (int off = NT / 2; off > 0; off >>= 1) {
        if (t < off) red[t] += red[t + off];
        __syncthreads();
    }
    if (t == 0) bsum[sel * NB + b] = red[0];
}

__global__ void k_scan_bsum(int* __restrict__ bsum) {
    __shared__ int sh[NB];
    int t = threadIdx.x;
    for (int sel = 0; sel < 2; ++sel) {
        int v = bsum[sel * NB + t];
        sh[t] = v;
        __syncthreads();
        for (int off = 1; off < NB; off <<= 1) {
            int u = (t >= off) ? sh[t - off] : 0;
            __syncthreads();
            sh[t] += u;
            __syncthreads();
        }
        bsum[sel * NB + t] = sh[t] - v;
        __syncthreads();
    }
}

__global__ void k_scan_write(const int* __restrict__ cntA, int nA, int* __restrict__ rpA,
                             const int* __restrict__ cntB, int nB, int* __restrict__ rpB,
                             const int* __restrict__ tsum, const int* __restrict__ bsum) {
    __shared__ int sh[NT];
    int sel = blockIdx.x / NB;
    int b   = blockIdx.x % NB;
    const int* cnt = sel ? cntB : cntA;
    int* rp = sel ? rpB : rpA;
    int n = sel ? nB : nA;
    int sub = (n + NB * NT - 1) / (NB * NT);
    int t = threadIdx.x;
    int gt = b * NT + t;
    int v = tsum[(size_t)sel * NB * NT + gt];
    sh[t] = v;
    __syncthreads();
    for (int off = 1; off < NT; off <<= 1) {
        int u = (t >= off) ? sh[t - off] : 0;
        __syncthreads();
        sh[t] += u;
        __syncthreads();
    }
    int base = bsum[sel * NB + b] + sh[t] - v;
    long long lo = (long long)gt * sub;
    long long hi = lo + sub; if (hi > n) hi = n;
    for (long long i = lo; i < hi; ++i) { int c = cnt[i]; rp[i] = base; base += c; }
    if (lo < n && hi == n) rp[n] = base;
}

// ---------- in-place bucket sort: staged (bucket-grouped) -> exact CSR -------
__global__ __launch_bounds__(256) void k_bsort2(
        const int* __restrict__ gsA, const int* __restrict__ rpA, int* __restrict__ csrA,
        int nA, int nbA,
        const int* __restrict__ gsB, const int* __restrict__ rpB, int* __restrict__ csrB,
        int nB) {
    __shared__ int buf[SORTCAP];
    __shared__ int cur[BKT];
    int b = blockIdx.x;
    const int* gs; const int* rp; int* csr; int n; int bb;
    if (b < nbA) { gs = gsA; rp = rpA; csr = csrA; n = nA; bb = b; }
    else         { gs = gsB; rp = rpB; csr = csrB; n = nB; bb = b - nbA; }
    int t = threadIdx.x;
    int s0 = gs[bb], s1 = gs[bb + 1];
    int cnt = s1 - s0;
    for (int i = t; i < cnt; i += 256) buf[i] = csr[s0 + i];
    if (t < BKT) { int v = bb * BKT + t; cur[t] = (v < n) ? rp[v] : 0; }
    __syncthreads();
    for (int i = t; i < cnt; i += 256) {
        int p = buf[i];
        int pos = atomicAdd(&cur[p & (BKT - 1)], 1);
        csr[pos] = p >> BSH;
    }
}

// ---------- quad reduce via DPP (xor1 then xor2, pure VALU) -------------------
__device__ __forceinline__ float qred(float x) {
    x += __int_as_float(__builtin_amdgcn_update_dpp(
            0, __float_as_int(x), 0xB1 /*quad_perm [1,0,3,2]*/, 0xF, 0xF, true));
    x += __int_as_float(__builtin_amdgcn_update_dpp(
            0, __float_as_int(x), 0x4E /*quad_perm [2,3,0,1]*/, 0xF, 0xF, true));
    return x;
}

// ---------- fused: out[v] = relu?( xdst[v]@Ws^T + b + mean gather @ Wn^T ) ----
// 8 nodes/block, 32 lanes/node. Gather: lane = (el=d&3 edge slot, q=d>>2 quarter);
// 8 edges/iteration -> two independent float4 loads in flight per lane.
// Cross-edge reduce = xor1+xor2 -> DPP quad_perm adds (off the LDS pipe).
__device__ __forceinline__ void fused_body(
        const float* __restrict__ xsrc, const float* __restrict__ xdst,
        const int* __restrict__ rowptr, const int* __restrict__ csr_src,
        const float* __restrict__ Ws, const float* __restrict__ Wn,
        const float* __restrict__ bias,
        float* __restrict__ out, int n, int do_relu, int bb) {
    __shared__ float WsT[DD * WP], WnT[DD * WP], bsh[DD];
    __shared__ float xrow[8][DD], mrow[8][DD];
    int tid = threadIdx.x;
    for (int i = tid; i < DD * DD; i += 256) {
        int r = i >> 5, c = i & 31;
        WsT[c * WP + r] = Ws[i];
        WnT[c * WP + r] = Wn[i];
    }
    if (tid < DD) bsh[tid] = bias[tid];
    int g = tid >> 5;
    int d = tid & 31;
    int v = bb * 8 + g;
    if (v < n) {
        int rs = rowptr[v], re = rowptr[v + 1];
        int el = d & 3;    // edge slot 0..3
        int q  = d >> 2;   // float4 quarter 0..7
        const float4* x4p = (const float4*)xsrc;
        float ax = 0.f, ay = 0.f, az = 0.f, aw = 0.f;
        for (int j0 = rs; j0 < re; j0 += 32) {
            int nj = re - j0; if (nj > 32) nj = 32;
            int myi = (d < nj) ? csr_src[j0 + d] : 0;
            for (int c0 = 0; c0 < nj; c0 += 8) {
                int jj0 = c0 + el;
                int jj1 = c0 + 4 + el;
                int s0 = __shfl(myi, jj0, 32);
                int s1 = __shfl(myi, jj1, 32);
                if (jj0 < nj) {
                    float4 x4 = x4p[(unsigned)s0 * 8u + q];   // 32-bit voffset
                    ax += x4.x; ay += x4.y; az += x4.z; aw += x4.w;
                }
                if (jj1 < nj) {
                    float4 x4 = x4p[(unsigned)s1 * 8u + q];
                    ax += x4.x; ay += x4.y; az += x4.z; aw += x4.w;
                }
            }
        }
        ax = qred(ax); ay = qred(ay); az = qred(az); aw = qred(aw);
        float rinv = 1.0f / fmaxf((float)(re - rs), 1.0f);
        if (el == 0) {
            float4 m4; m4.x = ax * rinv; m4.y = ay * rinv; m4.z = az * rinv; m4.w = aw * rinv;
            ((float4*)(&mrow[g][0]))[q] = m4;
        }
        xrow[g][d] = xdst[(unsigned)v * DD + d];
    }
    __syncthreads();
    if (v < n) {
        float s2 = bsh[d];
#pragma unroll
        for (int k = 0; k < DD; ++k) {
            s2 += xrow[g][k] * WsT[k * WP + d] + mrow[g][k] * WnT[k * WP + d];
        }
        if (do_relu) s2 = fmaxf(s2, 0.f);
        out[(unsigned)v * DD + d] = s2;
    }
}

__global__ __launch_bounds__(256) void k_fused(
        const float* __restrict__ xsrc, const float* __restrict__ xdst,
        const int* __restrict__ rowptr, const int* __restrict__ csr_src,
        const float* __restrict__ Ws, const float* __restrict__ Wn,
        const float* __restrict__ bias,
        float* __restrict__ out, int n, int do_relu) {
    fused_body(xsrc, xdst, rowptr, csr_src, Ws, Wn, bias, out, n, do_relu, blockIdx.x);
}

// merged layer-1 pair (independent relations, one launch)
__global__ __launch_bounds__(256) void k_fused2(
        const float* xsrcA, const float* xdstA, const int* rpA, const int* csrA,
        const float* WsA, const float* WnA, const float* bA, float* outA, int nA, int blocksA,
        const float* xsrcB, const float* xdstB, const int* rpB, const int* csrB,
        const float* WsB, const float* WnB, const float* bB, float* outB, int nB,
        int do_relu) {
    int b = blockIdx.x;
    bool A = b < blocksA;
    fused_body(A ? xsrcA : xsrcB, A ? xdstA : xdstB, A ? rpA : rpB, A ? csrA : csrB,
               A ? WsA : WsB, A ? WnA : WnB, A ? bA : bB, A ? outA : outB,
               A ? nA : nB, do_relu, A ? b : b - blocksA);
}

extern "C" void kernel_launch(void* const* d_in, const int* in_sizes, int n_in,
                              void* d_out, int out_size, void* d_ws, size_t ws_size,
                              hipStream_t stream) {
    const float* x_user = (const float*)d_in[0];
    const float* x_item = (const float*)d_in[1];
    const int*   ui_src = (const int*)d_in[2];
    const int*   ui_dst = (const int*)d_in[3];
    const int*   iu_src = (const int*)d_in[4];
    const int*   iu_dst = (const int*)d_in[5];
    const float* Ws_ui1 = (const float*)d_in[6];
    const float* Wn_ui1 = (const float*)d_in[7];
    const float* Ws_iu1 = (const float*)d_in[8];
    const float* Wn_iu1 = (const float*)d_in[9];
    const float* Ws_ui2 = (const float*)d_in[10];
    const float* Wn_ui2 = (const float*)d_in[11];
    const float* Ws_iu2 = (const float*)d_in[12];
    const float* Wn_iu2 = (const float*)d_in[13];
    const float* b_ui1  = (const float*)d_in[14];
    const float* b_iu1  = (const float*)d_in[15];
    const float* b_ui2  = (const float*)d_in[16];
    const float* b_iu2  = (const float*)d_in[17];

    int NU = in_sizes[0] / DD;
    int NI = in_sizes[1] / DD;
    int E  = in_sizes[2];
    int NBI = (NI + BKT - 1) >> BSH;
    int NBU = (NU + BKT - 1) >> BSH;
    int NMAX = (NU > NI) ? NU : NI;

    // ---- persistent workspace ----
    char* wp = (char*)d_ws;
    float* H_item = (float*)wp;  wp += (size_t)NI * DD * sizeof(float);   // layer-1 h_item
    int* csr_ui   = (int*)wp;    wp += (size_t)E * sizeof(int);
    int* csr_iu   = (int*)wp;    wp += (size_t)E * sizeof(int);
    int* rp_item  = (int*)wp;    wp += (size_t)(NI + 1) * sizeof(int);
    int* rp_user  = (int*)wp;

    // ---- transient arrays alias H_item (dead until layer 1 output) ----
    int* tr = (int*)H_item;
    int* bcntI = tr;  tr += MAXB;
    int* bcntU = tr;  tr += MAXB;
    int* gsI   = tr;  tr += MAXB + 1;
    int* gsU   = tr;  tr += MAXB + 1;
    int* curI  = tr;  tr += MAXB;
    int* curU  = tr;  tr += MAXB;
    int* cntI  = tr;  tr += NMAX;
    int* cntU  = tr;  tr += NMAX;
    int* tsum  = tr;  tr += 2 * NB * NT;
    int* bsum  = tr;

    float* h_user = (float*)d_out;                    // layer-1 h_user lives in d_out.user
    float* o_item = h_user + (size_t)NU * DD;         // final o_item slot

    int EB = (E + PCH - 1) / PCH;

    // ---- CSR build: bucket partition -> per-dst counts -> scan -> local sort
    (void)hipMemsetAsync(bcntI, 0, (size_t)2 * MAXB * sizeof(int), stream);
    hipLaunchKernelGGL(k_bhist, dim3(2 * EB), dim3(256), 0, stream,
                       ui_dst, bcntI, iu_dst, bcntU, E, EB);
    hipLaunchKernelGGL(k_bscan, dim3(1), dim3(256), 0, stream,
                       bcntI, gsI, curI, NBI, bcntU, gsU, curU, NBU);
    hipLaunchKernelGGL(k_part, dim3(2 * EB), dim3(256), 0, stream,
                       ui_src, ui_dst, curI, csr_ui,
                       iu_src, iu_dst, curU, csr_iu, E, EB);
    hipLaunchKernelGGL(k_dhist2, dim3(NBI + NBU), dim3(256), 0, stream,
                       gsI, csr_ui, cntI, NI, NBI, gsU, csr_iu, cntU, NU);
    hipLaunchKernelGGL(k_scan_partial, dim3(2 * NB), dim3(NT), 0, stream,
                       cntI, NI, cntU, NU, tsum, bsum);
    hipLaunchKernelGGL(k_scan_bsum, dim3(1), dim3(NB), 0, stream, bsum);
    hipLaunchKernelGGL(k_scan_write, dim3(2 * NB), dim3(NT), 0, stream,
                       cntI, NI, rp_item, cntU, NU, rp_user, tsum, bsum);
    hipLaunchKernelGGL(k_bsort2, dim3(NBI + NBU), dim3(256), 0, stream,
                       gsI, rp_item, csr_ui, NI, NBI, gsU, rp_user, csr_iu, NU);

    // ---- layer 1 (relu), both relations in one launch ----
    int NBIb = (NI + 7) / 8, NBUb = (NU + 7) / 8;
    hipLaunchKernelGGL(k_fused2, dim3(NBIb + NBUb), dim3(256), 0, stream,
                       x_user, x_item, rp_item, csr_ui, Ws_ui1, Wn_ui1, b_ui1, H_item, NI, NBIb,
                       x_item, x_user, rp_user, csr_iu, Ws_iu1, Wn_iu1, b_iu1, h_user, NU, 1);

    // ---- layer 2 (no relu): o_item first (reads h_user), then o_user in place
    hipLaunchKernelGGL(k_fused, dim3(NBIb), dim3(256), 0, stream,
                       h_user, H_item, rp_item, csr_ui, Ws_ui2, Wn_ui2, b_ui2,
                       o_item, NI, 0);
    hipLaunchKernelGGL(k_fused, dim3(NBUb), dim3(256), 0, stream,
                       H_item, h_user, rp_user, csr_iu, Ws_iu2, Wn_iu2, b_iu2,
                       h_user, NU, 0);
}

// Round 10
// 422.807 us; speedup vs baseline: 2.4597x; 1.0014x over previous
//
#include <hip/hip_runtime.h>

#define DD   32
#define BKT  128      // dsts per bucket (power of two)
#define BSH  7        // log2(BKT)
#define PCH  4096     // edges per partition/hist block
#define MAXB 2048     // padded bucket-count (>= nbkt)
#define NB   256      // scan blocks per array
#define NT   256      // scan threads per block
#define SORTCAP 8192  // max edges per bucket for in-place sort (mean ~1280)
#define WSETF 2080    // floats per weight-set: 512*2 (WsT2) + 512*2 (WnT2) + 32 (bias)

// ---------- bucket histogram (both relations, LDS pre-aggregated) ------------
__global__ void k_bhist(const int* __restrict__ dstA, int* __restrict__ cntA,
                        const int* __restrict__ dstB, int* __restrict__ cntB,
                        int E, int blocksPer) {
    __shared__ int h[MAXB];
    int b = blockIdx.x;
    const int* dst = (b < blocksPer) ? dstA : dstB;
    int* cnt       = (b < blocksPer) ? cntA : cntB;
    int bb         = (b < blocksPer) ? b : b - blocksPer;
    int t = threadIdx.x;
    for (int i = t; i < MAXB; i += 256) h[i] = 0;
    __syncthreads();
    int lo = bb * PCH;
    for (int k = 0; k < PCH / 256; ++k) {
        int i = lo + t + k * 256;
        if (i < E) atomicAdd(&h[dst[i] >> BSH], 1);
    }
    __syncthreads();
    for (int i = t; i < MAXB; i += 256) { int c = h[i]; if (c) atomicAdd(&cnt[i], c); }
}

// ---------- scan bucket counts -> gscan[nbkt+1] and cursor copy --------------
__global__ void k_bscan(const int* __restrict__ cntA, int* __restrict__ gsA, int* __restrict__ curA, int nbktA,
                        const int* __restrict__ cntB, int* __restrict__ gsB, int* __restrict__ curB, int nbktB) {
    __shared__ int sh[MAXB];
    __shared__ int red[256];
    int t = threadIdx.x;
    for (int sel = 0; sel < 2; ++sel) {
        const int* cnt = sel ? cntB : cntA;
        int* gs  = sel ? gsB : gsA;
        int* cur = sel ? curB : curA;
        int nbkt = sel ? nbktB : nbktA;
        for (int i = t; i < MAXB; i += 256) sh[i] = (i < nbkt) ? cnt[i] : 0;
        __syncthreads();
        int base = t * 8;
        int loc[8]; int tot = 0;
        for (int j = 0; j < 8; ++j) { loc[j] = sh[base + j]; tot += loc[j]; }
        red[t] = tot;
        __syncthreads();
        for (int off = 1; off < 256; off <<= 1) {
            int v = (t >= off) ? red[t - off] : 0;
            __syncthreads();
            red[t] += v;
            __syncthreads();
        }
        int run = red[t] - tot;
        for (int j = 0; j < 8; ++j) { sh[base + j] = run; run += loc[j]; }
        __syncthreads();
        for (int i = t; i < nbkt; i += 256) { gs[i] = sh[i]; cur[i] = sh[i]; }
        if (t == 255) gs[nbkt] = red[255];
        __syncthreads();
    }
}

// ---------- partition: staged[pos] = (src<<BSH) | (dst & (BKT-1)) ------------
__global__ void k_part(const int* __restrict__ srcA, const int* __restrict__ dstA,
                       int* __restrict__ curA, int* __restrict__ stA,
                       const int* __restrict__ srcB, const int* __restrict__ dstB,
                       int* __restrict__ curB, int* __restrict__ stB,
                       int E, int blocksPer) {
    __shared__ int pk[PCH];
    __shared__ unsigned short bkl[PCH];
    __shared__ int hist[MAXB];
    __shared__ int basev[MAXB];
    __shared__ int gb[MAXB];
    __shared__ int red[256];
    int b = blockIdx.x;
    const int* src; const int* dst; int* cur; int* st; int bb;
    if (b < blocksPer) { src = srcA; dst = dstA; cur = curA; st = stA; bb = b; }
    else               { src = srcB; dst = dstB; cur = curB; st = stB; bb = b - blocksPer; }
    int t = threadIdx.x;
    int lo = bb * PCH;
    int cntE = E - lo; if (cntE > PCH) cntE = PCH;

    for (int i = t; i < MAXB; i += 256) hist[i] = 0;
    __syncthreads();
    for (int k = 0; k < PCH / 256; ++k) {
        int i = t + k * 256;
        if (i < cntE) atomicAdd(&hist[dst[lo + i] >> BSH], 1);
    }
    __syncthreads();
    {
        int base = t * 8;
        int loc[8]; int tot = 0;
        for (int j = 0; j < 8; ++j) { loc[j] = hist[base + j]; tot += loc[j]; }
        red[t] = tot;
        __syncthreads();
        for (int off = 1; off < 256; off <<= 1) {
            int v = (t >= off) ? red[t - off] : 0;
            __syncthreads();
            red[t] += v;
            __syncthreads();
        }
        int run = red[t] - tot;
        for (int j = 0; j < 8; ++j) { basev[base + j] = run; run += loc[j]; }
    }
    __syncthreads();
    for (int i = t; i < MAXB; i += 256) hist[i] = 0;
    __syncthreads();
    for (int k = 0; k < PCH / 256; ++k) {
        int i = t + k * 256;
        if (i < cntE) {
            int s = src[lo + i], d = dst[lo + i];
            int bk = d >> BSH;
            int pos = basev[bk] + atomicAdd(&hist[bk], 1);
            pk[pos]  = (s << BSH) | (d & (BKT - 1));
            bkl[pos] = (unsigned short)bk;
        }
    }
    __syncthreads();
    for (int i = t; i < MAXB; i += 256) { int c = hist[i]; gb[i] = c ? atomicAdd(&cur[i], c) : 0; }
    __syncthreads();
    for (int i = t; i < cntE; i += 256) {
        int bk = bkl[i];
        st[gb[bk] + (i - basev[bk])] = pk[i];
    }
}

// ---------- per-dst degree from staged bucket lists --------------------------
__global__ void k_dhist2(const int* __restrict__ gsA, const int* __restrict__ stA,
                         int* __restrict__ cntA, int nA, int nbA,
                         const int* __restrict__ gsB, const int* __restrict__ stB,
                         int* __restrict__ cntB, int nB) {
    __shared__ int h[BKT];
    int b = blockIdx.x;
    const int* gs; const int* st; int* cnt; int n; int bb;
    if (b < nbA) { gs = gsA; st = stA; cnt = cntA; n = nA; bb = b; }
    else         { gs = gsB; st = stB; cnt = cntB; n = nB; bb = b - nbA; }
    int t = threadIdx.x;
    if (t < BKT) h[t] = 0;
    __syncthreads();
    int s0 = gs[bb], s1 = gs[bb + 1];
    for (int i = s0 + t; i < s1; i += 256) atomicAdd(&h[st[i] & (BKT - 1)], 1);
    __syncthreads();
    if (t < BKT) { int v = bb * BKT + t; if (v < n) cnt[v] = h[t]; }
}

// ---------- scan passes over per-dst counts -> rowptr ------------------------
__global__ void k_scan_partial(const int* __restrict__ cntA, int nA,
                               const int* __restrict__ cntB, int nB,
                               int* __restrict__ tsum, int* __restrict__ bsum) {
    __shared__ int red[NT];
    int sel = blockIdx.x / NB;
    int b   = blockIdx.x % NB;
    const int* cnt = sel ? cntB : cntA;
    int n = sel ? nB : nA;
    int sub = (n + NB * NT - 1) / (NB * NT);
    int t = threadIdx.x;
    int gt = b * NT + t;
    long long lo = (long long)gt * sub;
    int s = 0;
    for (int i = 0; i < sub; ++i) {
        long long idx = lo + i;
        if (idx < n) s += cnt[idx];
    }
    tsum[(size_t)sel * NB * NT + gt] = s;
    red[t] = s;
    __syncthreads();
    for (int off = NT / 2; off > 0; off >>= 1) {
        if (t < off) red[t] += red[t + off];
        __syncthreads();
    }
    if (t == 0) bsum[sel * NB + b] = red[0];
}

__global__ void k_scan_bsum(int* __restrict__ bsum) {
    __shared__ int sh[NB];
    int t = threadIdx.x;
    for (int sel = 0; sel < 2; ++sel) {
        int v = bsum[sel * NB + t];
        sh[t] = v;
        __syncthreads();
        for (int off = 1; off < NB; off <<= 1) {
            int u = (t >= off) ? sh[t - off] : 0;
            __syncthreads();
            sh[t] += u;
            __syncthreads();
        }
        bsum[sel * NB + t] = sh[t] - v;
        __syncthreads();
    }
}

__global__ void k_scan_write(const int* __restrict__ cntA, int nA, int* __restrict__ rpA,
                             const int* __restrict__ cntB, int nB, int* __restrict__ rpB,
                             const int* __restrict__ tsum, const int* __restrict__ bsum) {
    __shared__ int sh[NT];
    int sel = blockIdx.x / NB;
    int b   = blockIdx.x % NB;
    const int* cnt = sel ? cntB : cntA;
    int* rp = sel ? rpB : rpA;
    int n = sel ? nB : nA;
    int sub = (n + NB * NT - 1) / (NB * NT);
    int t = threadIdx.x;
    int gt = b * NT + t;
    int v = tsum[(size_t)sel * NB * NT + gt];
    sh[t] = v;
    __syncthreads();
    for (int off = 1; off < NT; off <<= 1) {
        int u = (t >= off) ? sh[t - off] : 0;
        __syncthreads();
        sh[t] += u;
        __syncthreads();
    }
    int base = bsum[sel * NB + b] + sh[t] - v;
    long long lo = (long long)gt * sub;
    long long hi = lo + sub; if (hi > n) hi = n;
    for (long long i = lo; i < hi; ++i) { int c = cnt[i]; rp[i] = base; base += c; }
    if (lo < n && hi == n) rp[n] = base;
}

// ---------- in-place bucket sort: staged (bucket-grouped) -> exact CSR -------
__global__ __launch_bounds__(256) void k_bsort2(
        const int* __restrict__ gsA, const int* __restrict__ rpA, int* __restrict__ csrA,
        int nA, int nbA,
        const int* __restrict__ gsB, const int* __restrict__ rpB, int* __restrict__ csrB,
        int nB) {
    __shared__ int buf[SORTCAP];
    __shared__ int cur[BKT];
    int b = blockIdx.x;
    const int* gs; const int* rp; int* csr; int n; int bb;
    if (b < nbA) { gs = gsA; rp = rpA; csr = csrA; n = nA; bb = b; }
    else         { gs = gsB; rp = rpB; csr = csrB; n = nB; bb = b - nbA; }
    int t = threadIdx.x;
    int s0 = gs[bb], s1 = gs[bb + 1];
    int cnt = s1 - s0;
    for (int i = t; i < cnt; i += 256) buf[i] = csr[s0 + i];
    if (t < BKT) { int v = bb * BKT + t; cur[t] = (v < n) ? rp[v] : 0; }
    __syncthreads();
    for (int i = t; i < cnt; i += 256) {
        int p = buf[i];
        int pos = atomicAdd(&cur[p & (BKT - 1)], 1);
        csr[pos] = p >> BSH;
    }
}

// ---------- weight prep: 4 sets of (WsT2 | WnT2 | bias), pair-packed ----------
// WsT2 float2[k2*32+d] = (Ws[d][2k2], Ws[d][2k2+1])  -- transposed + k-paired
__global__ void k_wprep(const float* W0s, const float* W0n, const float* b0,
                        const float* W1s, const float* W1n, const float* b1,
                        const float* W2s, const float* W2n, const float* b2,
                        const float* W3s, const float* W3n, const float* b3,
                        float* __restrict__ out) {
    int s = blockIdx.x;
    const float* Ws = (s == 0) ? W0s : (s == 1) ? W1s : (s == 2) ? W2s : W3s;
    const float* Wn = (s == 0) ? W0n : (s == 1) ? W1n : (s == 2) ? W2n : W3n;
    const float* bb = (s == 0) ? b0  : (s == 1) ? b1  : (s == 2) ? b2  : b3;
    float* o = out + (size_t)s * WSETF;
    int t = threadIdx.x;
    for (int i = t; i < 512; i += 256) {
        int k2 = i >> 5, d = i & 31;
        ((float2*)o)[i]       = *(const float2*)(Ws + d * DD + 2 * k2);
        ((float2*)o)[512 + i] = *(const float2*)(Wn + d * DD + 2 * k2);
    }
    if (t < DD) o[2048 + t] = bb[t];
}

// ---------- quad reduce via DPP (xor1 then xor2, pure VALU) -------------------
__device__ __forceinline__ float qred(float x) {
    x += __int_as_float(__builtin_amdgcn_update_dpp(
            0, __float_as_int(x), 0xB1 /*quad_perm [1,0,3,2]*/, 0xF, 0xF, true));
    x += __int_as_float(__builtin_amdgcn_update_dpp(
            0, __float_as_int(x), 0x4E /*quad_perm [2,3,0,1]*/, 0xF, 0xF, true));
    return x;
}

// ---------- packed f32 FMA (VOP3P v_pk_fma_f32): d = a*b + c ------------------
__device__ __forceinline__ float2 pkfma(float2 a, float2 b, float2 c) {
    float2 d;
    asm("v_pk_fma_f32 %0, %1, %2, %3" : "=v"(d) : "v"(a), "v"(b), "v"(c));
    return d;
}

// ---------- fused: out[v] = relu?( xdst[v]@Ws^T + b + mean gather @ Wn^T ) ----
// 8 nodes/block, 32 lanes/node. Gather: lane = (el=d&3 edge slot, q=d>>2 quarter).
// GEMM: pair-packed transposed weights staged linearly into LDS (float4 copy),
// inner loop = 32 v_pk_fma_f32 on two accumulators; all LDS reads are b64.
__device__ __forceinline__ void fused_body(
        const float* __restrict__ xsrc, const float* __restrict__ xdst,
        const int* __restrict__ rowptr, const int* __restrict__ csr_src,
        const float* __restrict__ wset,
        float* __restrict__ out, int n, int do_relu, int bb) {
    __shared__ float wbuf[WSETF];
    __shared__ float xm[8][2 * DD];   // [g][0..31]=x row, [g][32..63]=mean row
    int tid = threadIdx.x;
    // stage weight-set (linear, vectorized, no transpose)
    for (int i = tid; i < WSETF / 4; i += 256)
        ((float4*)wbuf)[i] = ((const float4*)wset)[i];
    int g = tid >> 5;
    int d = tid & 31;
    int v = bb * 8 + g;
    if (v < n) {
        xm[g][d] = xdst[(unsigned)v * DD + d];   // hoisted self-row load
        int rs = rowptr[v], re = rowptr[v + 1];
        int el = d & 3;    // edge slot 0..3
        int q  = d >> 2;   // float4 quarter 0..7
        const float4* x4p = (const float4*)xsrc;
        float ax = 0.f, ay = 0.f, az = 0.f, aw = 0.f;
        for (int j0 = rs; j0 < re; j0 += 32) {
            int nj = re - j0; if (nj > 32) nj = 32;
            int myi = (d < nj) ? csr_src[j0 + d] : 0;
            for (int c0 = 0; c0 < nj; c0 += 8) {
                int jj0 = c0 + el;
                int jj1 = c0 + 4 + el;
                int s0 = __shfl(myi, jj0, 32);
                int s1 = __shfl(myi, jj1, 32);
                if (jj0 < nj) {
                    float4 x4 = x4p[(unsigned)s0 * 8u + q];
                    ax += x4.x; ay += x4.y; az += x4.z; aw += x4.w;
                }
                if (jj1 < nj) {
                    float4 x4 = x4p[(unsigned)s1 * 8u + q];
                    ax += x4.x; ay += x4.y; az += x4.z; aw += x4.w;
                }
            }
        }
        ax = qred(ax); ay = qred(ay); az = qred(az); aw = qred(aw);
        float rinv = 1.0f / fmaxf((float)(re - rs), 1.0f);
        if (el == 0) {
            float4 m4; m4.x = ax * rinv; m4.y = ay * rinv; m4.z = az * rinv; m4.w = aw * rinv;
            ((float4*)(&xm[g][DD]))[q] = m4;
        }
    }
    __syncthreads();
    if (v < n) {
        const float2* Ws2 = (const float2*)wbuf;          // [0..511]
        const float2* Wn2 = ((const float2*)wbuf) + 512;  // [512..1023]
        const float2* xv2 = (const float2*)(&xm[g][0]);
        const float2* mv2 = (const float2*)(&xm[g][DD]);
        float2 accS = make_float2(0.f, 0.f);
        float2 accN = make_float2(0.f, 0.f);
#pragma unroll
        for (int k2 = 0; k2 < 16; ++k2) {
            accS = pkfma(xv2[k2], Ws2[k2 * 32 + d], accS);
            accN = pkfma(mv2[k2], Wn2[k2 * 32 + d], accN);
        }
        float s2 = accS.x + accS.y + accN.x + accN.y + wbuf[2048 + d];
        if (do_relu) s2 = fmaxf(s2, 0.f);
        out[(unsigned)v * DD + d] = s2;
    }
}

__global__ __launch_bounds__(256) void k_fused(
        const float* __restrict__ xsrc, const float* __restrict__ xdst,
        const int* __restrict__ rowptr, const int* __restrict__ csr_src,
        const float* __restrict__ wset,
        float* __restrict__ out, int n, int do_relu) {
    fused_body(xsrc, xdst, rowptr, csr_src, wset, out, n, do_relu, blockIdx.x);
}

// merged layer-1 pair (independent relations, one launch)
__global__ __launch_bounds__(256) void k_fused2(
        const float* xsrcA, const float* xdstA, const int* rpA, const int* csrA,
        const float* wsetA, float* outA, int nA, int blocksA,
        const float* xsrcB, const float* xdstB, const int* rpB, const int* csrB,
        const float* wsetB, float* outB, int nB, int do_relu) {
    int b = blockIdx.x;
    bool A = b < blocksA;
    fused_body(A ? xsrcA : xsrcB, A ? xdstA : xdstB, A ? rpA : rpB, A ? csrA : csrB,
               A ? wsetA : wsetB, A ? outA : outB,
               A ? nA : nB, do_relu, A ? b : b - blocksA);
}

extern "C" void kernel_launch(void* const* d_in, const int* in_sizes, int n_in,
                              void* d_out, int out_size, void* d_ws, size_t ws_size,
                              hipStream_t stream) {
    const float* x_user = (const float*)d_in[0];
    const float* x_item = (const float*)d_in[1];
    const int*   ui_src = (const int*)d_in[2];
    const int*   ui_dst = (const int*)d_in[3];
    const int*   iu_src = (const int*)d_in[4];
    const int*   iu_dst = (const int*)d_in[5];
    const float* Ws_ui1 = (const float*)d_in[6];
    const float* Wn_ui1 = (const float*)d_in[7];
    const float* Ws_iu1 = (const float*)d_in[8];
    const float* Wn_iu1 = (const float*)d_in[9];
    const float* Ws_ui2 = (const float*)d_in[10];
    const float* Wn_ui2 = (const float*)d_in[11];
    const float* Ws_iu2 = (const float*)d_in[12];
    const float* Wn_iu2 = (const float*)d_in[13];
    const float* b_ui1  = (const float*)d_in[14];
    const float* b_iu1  = (const float*)d_in[15];
    const float* b_ui2  = (const float*)d_in[16];
    const float* b_iu2  = (const float*)d_in[17];

    int NU = in_sizes[0] / DD;
    int NI = in_sizes[1] / DD;
    int E  = in_sizes[2];
    int NBI = (NI + BKT - 1) >> BSH;
    int NBU = (NU + BKT - 1) >> BSH;
    int NMAX = (NU > NI) ? NU : NI;

    // ---- persistent workspace ----
    char* wp = (char*)d_ws;
    float* H_item = (float*)wp;  wp += (size_t)NI * DD * sizeof(float);   // layer-1 h_item
    int* csr_ui   = (int*)wp;    wp += (size_t)E * sizeof(int);
    int* csr_iu   = (int*)wp;    wp += (size_t)E * sizeof(int);
    int* rp_item  = (int*)wp;    wp += (size_t)(NI + 1) * sizeof(int);
    int* rp_user  = (int*)wp;    wp += (size_t)(NU + 1) * sizeof(int);
    float* wprep  = (float*)wp;  wp += (size_t)4 * WSETF * sizeof(float);

    // ---- transient arrays alias H_item (dead until layer 1 output) ----
    int* tr = (int*)H_item;
    int* bcntI = tr;  tr += MAXB;
    int* bcntU = tr;  tr += MAXB;
    int* gsI   = tr;  tr += MAXB + 1;
    int* gsU   = tr;  tr += MAXB + 1;
    int* curI  = tr;  tr += MAXB;
    int* curU  = tr;  tr += MAXB;
    int* cntI  = tr;  tr += NMAX;
    int* cntU  = tr;  tr += NMAX;
    int* tsum  = tr;  tr += 2 * NB * NT;
    int* bsum  = tr;

    float* h_user = (float*)d_out;                    // layer-1 h_user lives in d_out.user
    float* o_item = h_user + (size_t)NU * DD;         // final o_item slot

    int EB = (E + PCH - 1) / PCH;

    // ---- weight prep (one-time, 4 blocks) ----
    hipLaunchKernelGGL(k_wprep, dim3(4), dim3(256), 0, stream,
                       Ws_ui1, Wn_ui1, b_ui1, Ws_iu1, Wn_iu1, b_iu1,
                       Ws_ui2, Wn_ui2, b_ui2, Ws_iu2, Wn_iu2, b_iu2, wprep);

    // ---- CSR build: bucket partition -> per-dst counts -> scan -> local sort
    (void)hipMemsetAsync(bcntI, 0, (size_t)2 * MAXB * sizeof(int), stream);
    hipLaunchKernelGGL(k_bhist, dim3(2 * EB), dim3(256), 0, stream,
                       ui_dst, bcntI, iu_dst, bcntU, E, EB);
    hipLaunchKernelGGL(k_bscan, dim3(1), dim3(256), 0, stream,
                       bcntI, gsI, curI, NBI, bcntU, gsU, curU, NBU);
    hipLaunchKernelGGL(k_part, dim3(2 * EB), dim3(256), 0, stream,
                       ui_src, ui_dst, curI, csr_ui,
                       iu_src, iu_dst, curU, csr_iu, E, EB);
    hipLaunchKernelGGL(k_dhist2, dim3(NBI + NBU), dim3(256), 0, stream,
                       gsI, csr_ui, cntI, NI, NBI, gsU, csr_iu, cntU, NU);
    hipLaunchKernelGGL(k_scan_partial, dim3(2 * NB), dim3(NT), 0, stream,
                       cntI, NI, cntU, NU, tsum, bsum);
    hipLaunchKernelGGL(k_scan_bsum, dim3(1), dim3(NB), 0, stream, bsum);
    hipLaunchKernelGGL(k_scan_write, dim3(2 * NB), dim3(NT), 0, stream,
                       cntI, NI, rp_item, cntU, NU, rp_user, tsum, bsum);
    hipLaunchKernelGGL(k_bsort2, dim3(NBI + NBU), dim3(256), 0, stream,
                       gsI, rp_item, csr_ui, NI, NBI, gsU, rp_user, csr_iu, NU);

    // ---- layer 1 (relu), both relations in one launch ----
    int NBIb = (NI + 7) / 8, NBUb = (NU + 7) / 8;
    hipLaunchKernelGGL(k_fused2, dim3(NBIb + NBUb), dim3(256), 0, stream,
                       x_user, x_item, rp_item, csr_ui, wprep + 0 * WSETF, H_item, NI, NBIb,
                       x_item, x_user, rp_user, csr_iu, wprep + 1 * WSETF, h_user, NU, 1);

    // ---- layer 2 (no relu): o_item first (reads h_user), then o_user in place
    hipLaunchKernelGGL(k_fused, dim3(NBIb), dim3(256), 0, stream,
                       h_user, H_item, rp_item, csr_ui, wprep + 2 * WSETF,
                       o_item, NI, 0);
    hipLaunchKernelGGL(k_fused, dim3(NBUb), dim3(256), 0, stream,
                       H_item, h_user, rp_user, csr_iu, wprep + 3 * WSETF,
                       h_user, NU, 0);
}